// Round 8
// baseline (359.316 us; speedup 1.0000x reference)
//
#include <hip/hip_runtime.h>
#include <math.h>

#define NH 32
#define NHK 8
#define HD 64
#define DMODEL 2048
#define LSEQ 2048
#define NB 2
#define QKV_N 3072   // 2048 q + 512 k + 512 v

typedef __attribute__((ext_vector_type(8))) short short8;
typedef __attribute__((ext_vector_type(4))) float floatx4;

__device__ __forceinline__ unsigned short f2bf(float f) {
  unsigned u = __float_as_uint(f);
  return (unsigned short)((u + 0x7FFFu + ((u >> 16) & 1u)) >> 16);  // RNE
}
__device__ __forceinline__ float bf2f(unsigned short v) {
  return __uint_as_float((unsigned)v << 16);
}
__device__ __forceinline__ float fast_exp2(float x) {
#if __has_builtin(__builtin_amdgcn_exp2f)
  return __builtin_amdgcn_exp2f(x);
#else
  return __expf(x * 0.69314718f);
#endif
}
// pack bf16(hi),bf16(lo) from two fp32 by truncation: 1 v_perm_b32
__device__ __forceinline__ unsigned pack_bf_trunc(float hi, float lo) {
  return __builtin_amdgcn_perm(__float_as_uint(hi), __float_as_uint(lo), 0x07060302u);
}
// async 16B global->LDS; lds base must be wave-uniform, lanes land at base+lane*16
__device__ __forceinline__ void stage16(const unsigned short* g,
                                        unsigned short* lds_wave_base, int lane) {
#if __has_builtin(__builtin_amdgcn_global_load_lds)
  __builtin_amdgcn_global_load_lds(
      (const __attribute__((address_space(1))) void*)(g),
      (__attribute__((address_space(3))) void*)(lds_wave_base), 16, 0, 0);
#else
  *(uint4*)(lds_wave_base + lane * 8) = *(const uint4*)g;
#endif
}
// scatter variant: per-lane global address
__device__ __forceinline__ void stage16g(const char* g_lane,
                                         unsigned short* lds_wave_base, int lane) {
#if __has_builtin(__builtin_amdgcn_global_load_lds)
  __builtin_amdgcn_global_load_lds(
      (const __attribute__((address_space(1))) void*)(g_lane),
      (__attribute__((address_space(3))) void*)(lds_wave_base), 16, 0, 0);
#else
  *(uint4*)(lds_wave_base + lane * 8) = *(const uint4*)g_lane;
#endif
}

// ---------------------------------------------------------------------------
// RoPE cos/sin table: tab[l][d] = (cos, sin), l<2048, d<32
// ---------------------------------------------------------------------------
__global__ __launch_bounds__(256) void rope_tab(float2* __restrict__ tab) {
  int i = blockIdx.x * 256 + threadIdx.x;  // L*32
  int d = i & 31, l = i >> 5;
  float invf = (float)pow(10000.0, -(double)d / 32.0);
  float ang = (float)l * invf;
  double sd, cd;
  sincos((double)ang, &sd, &cd);
  tab[i] = make_float2((float)cd, (float)sd);
}

// ---------------------------------------------------------------------------
// fp32 -> bf16 elementwise convert
// ---------------------------------------------------------------------------
__global__ __launch_bounds__(256) void cvt_bf16(const float* __restrict__ src,
                                                unsigned short* __restrict__ dst,
                                                int n4) {
  int i = blockIdx.x * 256 + threadIdx.x;
  if (i >= n4) return;
  float4 v = ((const float4*)src)[i];
  ushort4 o;
  o.x = f2bf(v.x); o.y = f2bf(v.y); o.z = f2bf(v.z); o.w = f2bf(v.w);
  ((ushort4*)dst)[i] = o;
}

// ---------------------------------------------------------------------------
// Wq|Wk|Wv -> one bf16 buffer, single launch
// ---------------------------------------------------------------------------
__global__ __launch_bounds__(256) void cvt_w3(const float* __restrict__ Wq,
                                              const float* __restrict__ Wk,
                                              const float* __restrict__ Wv,
                                              unsigned short* __restrict__ dst) {
  const int NQ = DMODEL * DMODEL / 4, NK = 512 * DMODEL / 4;
  int i = blockIdx.x * 256 + threadIdx.x;  // 0..NQ+2*NK-1
  const float* src;
  int off;
  if (i < NQ) { src = Wq; off = i; }
  else if (i < NQ + NK) { src = Wk; off = i - NQ; }
  else { src = Wv; off = i - NQ - NK; }
  float4 v = ((const float4*)src)[off];
  ushort4 o;
  o.x = f2bf(v.x); o.y = f2bf(v.y); o.z = f2bf(v.z); o.w = f2bf(v.w);
  ((ushort4*)dst)[i] = o;
}

// ---------------------------------------------------------------------------
// bf16 NT GEMM, m97 structure: 128x128 tile, BK=32, global_load_lds width=16,
// unpadded LDS with XOR-swizzled 16B chunks.  BF16C: C written bf16.
// ---------------------------------------------------------------------------
template <bool BF16C>
__global__ __launch_bounds__(256) void gemm2(const unsigned short* __restrict__ A,
                                             const unsigned short* __restrict__ B,
                                             void* __restrict__ Cv, int K, int ldc) {
  __shared__ unsigned short As[128 * 32];
  __shared__ unsigned short Bs[128 * 32];
  const int tid = threadIdx.x;
  const int wave = tid >> 6, lane = tid & 63;
  const int quad = lane >> 4, l16 = lane & 15;
  const int m0 = blockIdx.y * 128, n0 = blockIdx.x * 128;
  const int wm = (wave & 1) * 64, wn = (wave >> 1) * 64;

  const int srow = wave * 16 + (lane >> 2);
  const int schunk = (lane & 3) ^ ((lane >> 2) & 3);
  const unsigned short* Asrc = A + (size_t)(m0 + srow) * K + schunk * 8;
  const unsigned short* Bsrc = B + (size_t)(n0 + srow) * K + schunk * 8;
  unsigned short* AdstL = &As[wave * 512];
  unsigned short* AdstH = &As[2048 + wave * 512];
  unsigned short* BdstL = &Bs[wave * 512];
  unsigned short* BdstH = &Bs[2048 + wave * 512];
  const size_t rstep = (size_t)64 * K;

  const int sw = (quad ^ (l16 & 3)) * 8;
  floatx4 acc[4][4] = {};

  for (int k0 = 0; k0 < K; k0 += 32) {
    __syncthreads();
    stage16(Asrc + k0, AdstL, lane);
    stage16(Asrc + rstep + k0, AdstH, lane);
    stage16(Bsrc + k0, BdstL, lane);
    stage16(Bsrc + rstep + k0, BdstH, lane);
    __syncthreads();
    short8 af[4], bfr[4];
#pragma unroll
    for (int i = 0; i < 4; ++i)
      af[i] = *(const short8*)&As[(wm + i * 16 + l16) * 32 + sw];
#pragma unroll
    for (int j = 0; j < 4; ++j)
      bfr[j] = *(const short8*)&Bs[(wn + j * 16 + l16) * 32 + sw];
#pragma unroll
    for (int i = 0; i < 4; ++i)
#pragma unroll
      for (int j = 0; j < 4; ++j)
        acc[i][j] = __builtin_amdgcn_mfma_f32_16x16x32_bf16(af[i], bfr[j], acc[i][j], 0, 0, 0);
  }

#pragma unroll
  for (int i = 0; i < 4; ++i)
#pragma unroll
    for (int j = 0; j < 4; ++j)
#pragma unroll
      for (int r = 0; r < 4; ++r) {
        size_t idx = (size_t)(m0 + wm + i * 16 + quad * 4 + r) * ldc + n0 + wn + j * 16 + l16;
        if (BF16C)
          ((unsigned short*)Cv)[idx] = f2bf(acc[i][j][r]);
        else
          ((float*)Cv)[idx] = acc[i][j][r];
      }
}

// ---------------------------------------------------------------------------
// RoPE k (bf16 in) -> kb [B, HK, L, 64] bf16
// ---------------------------------------------------------------------------
__global__ __launch_bounds__(256) void ropek_cvt2(const unsigned short* __restrict__ qkvb,
                                                  const float2* __restrict__ tab,
                                                  unsigned short* __restrict__ kb) {
  int t = blockIdx.x * 256 + threadIdx.x;  // B*L*8*32 threads
  int d = t & 31;
  int rest = t >> 5;
  int khead = rest & 7;
  int bl = rest >> 3;
  int l = bl & (LSEQ - 1);
  int b = bl >> 11;
  const unsigned short* src = qkvb + (size_t)bl * QKV_N + DMODEL + khead * HD;
  float2 cs = tab[(size_t)l * 32 + d];
  float x1 = bf2f(src[d]), x2 = bf2f(src[d + 32]);
  unsigned short* dst = kb + ((size_t)((b * NHK + khead) * LSEQ + l)) * HD;
  dst[d] = f2bf(x1 * cs.x - x2 * cs.y);
  dst[d + 32] = f2bf(x2 * cs.x + x1 * cs.y);
}

// ---------------------------------------------------------------------------
// V transpose (bf16 in): vtb [B, HK, 80, L] (rows 0..63 = V^T, row 64 = ones,
// rows 65..79 poison but harmless: bf16(0xAAAA) ~ -3e-13)
// ---------------------------------------------------------------------------
__global__ __launch_bounds__(256) void vt_cvt2(const unsigned short* __restrict__ qkvb,
                                               unsigned short* __restrict__ vtb) {
  __shared__ unsigned short Lt[64][72];
  const int tt = blockIdx.x, kh = blockIdx.y, b = blockIdx.z;
  const int tid = threadIdx.x;
  const unsigned short* src =
      qkvb + ((size_t)(b * LSEQ + tt * 64)) * QKV_N + DMODEL + 512 + kh * HD;
  {
    int row = tid >> 2, c0 = (tid & 3) * 16;
    *(uint4*)&Lt[row][c0] = *(const uint4*)(src + (size_t)row * QKV_N + c0);
    *(uint4*)&Lt[row][c0 + 8] = *(const uint4*)(src + (size_t)row * QKV_N + c0 + 8);
  }
  __syncthreads();
  {
    int d = tid >> 2, seg = tid & 3;
    unsigned short o[16];
#pragma unroll
    for (int k = 0; k < 16; ++k) o[k] = Lt[seg * 16 + k][d];
    unsigned short* dst =
        vtb + ((size_t)((b * NHK + kh) * 80 + d)) * LSEQ + tt * 64 + seg * 16;
    *(uint4*)dst = *(uint4*)o;
    *(uint4*)(dst + 8) = *(uint4*)(o + 8);
  }
  if (tid < 64)
    vtb[((size_t)((b * NHK + kh) * 80 + 64)) * LSEQ + tt * 64 + tid] = 0x3F80;  // 1.0
}

// ---------------------------------------------------------------------------
// attn7: flash MFMA causal GQA attention, LDS-staged K/V, one 32-q subtile
// per block.  Grid (8=kh -> XCD pin, 64=subtile, 2=b) = 1024 blocks = 4/CU
// (LDS 36.9 KB/block) so barrier/DMA drains of one block hide behind the
// other three blocks' compute (m114 co-scheduling).  a = 63-blockIdx.y so
// the longest blocks dispatch first (short tail).  Block = 4 waves = 4
// q-heads of one kv group sharing one K tile + one V^T tile per kt, staged
// via global_load_lds with XOR-swizzled 16B chunks.  S^T orientation; RoPE
// fused into Q load; P round-trips wave-private LDS; row-sums via ones-row.
// ---------------------------------------------------------------------------
__global__ __launch_bounds__(256, 4) void attn7(const unsigned short* __restrict__ qkvb,
                                                const float2* __restrict__ tab,
                                                const unsigned short* __restrict__ kb,
                                                const unsigned short* __restrict__ vtb,
                                                unsigned short* __restrict__ out) {
  const int kh = blockIdx.x;              // 0..7 fastest -> XCD pin
  const int a = 63 - (int)blockIdx.y;     // longest blocks first
  const int b = blockIdx.z;
  const int wave = threadIdx.x >> 6, lane = threadIdx.x & 63;
  const int quad = lane >> 4, l16 = lane & 15;
  const int h = kh * 4 + wave;

  __shared__ unsigned short Ks[64 * 64];        // 8 KB  [key][d], xor-swizzled chunks
  __shared__ unsigned short Vs[80 * 64];        // 10 KB [d][key], xor-swizzled chunks
  __shared__ unsigned short Ps_all[4][32][72];  // 18 KB wave-private P tiles
  unsigned short(*Ps)[72] = Ps_all[wave];

  const char* kbaseB = (const char*)(kb + ((size_t)(b * NHK + kh) * LSEQ) * HD);
  const char* vbaseB = (const char*)(vtb + ((size_t)(b * NHK + kh) * 80) * LSEQ);
  const float QSCALE = 0.125f * 1.44269504f;  // 1/sqrt(64) * log2(e)

  const int qb = a * 32;
  const int last = a >> 1;

  // ---- Q frags with fused RoPE (B-operand: n=query=l16, k=d=quad*8+j) ----
  short8 qf[2][2];
#pragma unroll
  for (int i = 0; i < 2; ++i) {
    const int tok = qb + i * 16 + l16;
    const unsigned short* qr =
        qkvb + ((size_t)(b * LSEQ + tok)) * QKV_N + h * HD + quad * 8;
    uint4 lo = *(const uint4*)qr;         // d = quad*8 .. +7
    uint4 hi = *(const uint4*)(qr + 32);  // d+32
    const float2* tr = tab + (size_t)tok * 32 + quad * 8;
    float4 cs01 = ((const float4*)tr)[0];
    float4 cs23 = ((const float4*)tr)[1];
    float4 cs45 = ((const float4*)tr)[2];
    float4 cs67 = ((const float4*)tr)[3];
    float cosv[8] = {cs01.x, cs01.z, cs23.x, cs23.z, cs45.x, cs45.z, cs67.x, cs67.z};
    float sinv[8] = {cs01.y, cs01.w, cs23.y, cs23.w, cs45.y, cs45.w, cs67.y, cs67.w};
    const unsigned short* plo = (const unsigned short*)&lo;
    const unsigned short* phi = (const unsigned short*)&hi;
    unsigned short olo[8], ohi[8];
#pragma unroll
    for (int j = 0; j < 8; ++j) {
      float x1 = bf2f(plo[j]), x2 = bf2f(phi[j]);
      olo[j] = f2bf((x1 * cosv[j] - x2 * sinv[j]) * QSCALE);
      ohi[j] = f2bf((x2 * cosv[j] + x1 * sinv[j]) * QSCALE);
    }
    qf[i][0] = *(const short8*)olo;
    qf[i][1] = *(const short8*)ohi;
  }

  floatx4 O[2][5];
#pragma unroll
  for (int i = 0; i < 2; ++i)
#pragma unroll
    for (int j = 0; j < 5; ++j) O[i][j] = (floatx4){0.f, 0.f, 0.f, 0.f};

#pragma unroll 1
  for (int kt = 0; kt <= last; ++kt) {
    __syncthreads();  // all waves done reading previous Ks/Vs
    // ---- stage K (8 KB, calls 0..7) + V^T (10 KB, calls 8..17) ----
#pragma unroll
    for (int c = wave; c < 18; c += 4) {
      if (c < 8) {
        int o = c * 1024 + lane * 16;
        int row = o >> 7;                    // key 0..63
        int lgc = ((o >> 4) & 7) ^ (row & 7);
        stage16g(kbaseB + (size_t)(kt * 64 + row) * 128 + lgc * 16,
                 Ks + c * 512, lane);
      } else {
        int o = (c - 8) * 1024 + lane * 16;
        int row = o >> 7;                    // d-row 0..79
        int lgc = ((o >> 4) & 7) ^ (row & 7);
        stage16g(vbaseB + (size_t)row * (LSEQ * 2) + (size_t)kt * 128 + lgc * 16,
                 Vs + (c - 8) * 512, lane);
      }
    }
    __syncthreads();  // DMA drained

    // ---- K frags from LDS (A-operand: m=key=16t+l16, k=d=32hf+quad*8+j) ----
    short8 kf[4][2];
#pragma unroll
    for (int t = 0; t < 4; ++t)
#pragma unroll
      for (int hf = 0; hf < 2; ++hf) {
        int row = t * 16 + l16;
        int phys = (4 * hf + quad) ^ (row & 7);
        kf[t][hf] = *(const short8*)&Ks[row * 64 + phys * 8];
      }

    // ---- S^T = K Q^T ----
    floatx4 st[4][2];
#pragma unroll
    for (int t = 0; t < 4; ++t)
#pragma unroll
      for (int i = 0; i < 2; ++i) {
        floatx4 z = {0.f, 0.f, 0.f, 0.f};
        z = __builtin_amdgcn_mfma_f32_16x16x32_bf16(kf[t][0], qf[i][0], z, 0, 0, 0);
        st[t][i] = __builtin_amdgcn_mfma_f32_16x16x32_bf16(kf[t][1], qf[i][1], z, 0, 0, 0);
      }

    // ---- P = exp2(S^T) (+ causal mask on final kt), pack, b64 LDS write ----
    const bool masked = (kt == last);
    const int kofs = kt * 64 - qb;
#pragma unroll
    for (int t = 0; t < 4; ++t) {
      const int krow = kofs + 16 * t + quad * 4;
#pragma unroll
      for (int i = 0; i < 2; ++i) {
        const int qcol = 16 * i + l16;
        float sv[4];
#pragma unroll
        for (int r = 0; r < 4; ++r) {
          float v = st[t][i][r];
          if (masked && (krow + r > qcol)) v = -1e30f;
          sv[r] = fast_exp2(v);
        }
        uint2 w;
        w.x = pack_bf_trunc(sv[1], sv[0]);
        w.y = pack_bf_trunc(sv[3], sv[2]);
        *(uint2*)&Ps[16 * i + l16][16 * t + quad * 4] = w;
      }
    }

    // ---- O^T += V^T P^T ----
    short8 pf[2][2];
#pragma unroll
    for (int i = 0; i < 2; ++i)
#pragma unroll
      for (int hh = 0; hh < 2; ++hh)
        pf[i][hh] = *(const short8*)&Ps[16 * i + l16][32 * hh + quad * 8];
#pragma unroll
    for (int j = 0; j < 5; ++j) {
      int row = j * 16 + l16;
      short8 vf0 = *(const short8*)&Vs[row * 64 + ((quad ^ (row & 7)) * 8)];
      short8 vf1 = *(const short8*)&Vs[row * 64 + (((4 + quad) ^ (row & 7)) * 8)];
#pragma unroll
      for (int i = 0; i < 2; ++i) {
        O[i][j] = __builtin_amdgcn_mfma_f32_16x16x32_bf16(vf0, pf[i][0], O[i][j], 0, 0, 0);
        O[i][j] = __builtin_amdgcn_mfma_f32_16x16x32_bf16(vf1, pf[i][1], O[i][j], 0, 0, 0);
      }
    }
  }

  // ---- epilogue: l from ones-row tile (d=64 -> quad0,r0 lanes) ----
#pragma unroll
  for (int i = 0; i < 2; ++i) {
    float lv = __shfl(O[i][4][0], l16);  // lanes 0..15 hold l for q=16i+l16
    float inv = 1.0f / lv;
    const size_t obase =
        ((size_t)(b * LSEQ + qb + i * 16 + l16)) * DMODEL + h * HD;
#pragma unroll
    for (int j = 0; j < 4; ++j) {
      uint2 w;
      w.x = (unsigned)f2bf(O[i][j][0] * inv) | ((unsigned)f2bf(O[i][j][1] * inv) << 16);
      w.y = (unsigned)f2bf(O[i][j][2] * inv) | ((unsigned)f2bf(O[i][j][3] * inv) << 16);
      *(uint2*)&out[obase + j * 16 + quad * 4] = w;
    }
  }
}

extern "C" void kernel_launch(void* const* d_in, const int* in_sizes, int n_in,
                              void* d_out, int out_size, void* d_ws,
                              size_t ws_size, hipStream_t stream) {
  const float* x = (const float*)d_in[0];
  const float* Wq = (const float*)d_in[1];
  const float* Wk = (const float*)d_in[2];
  const float* Wv = (const float*)d_in[3];
  const float* Wo = (const float*)d_in[4];
  float* out = (float*)d_out;

  char* ws = (char*)d_ws;
  // layout (peak 64.5 MB):
  //   qkvb  bf16 [4096,3072] @ 0          25,165,824   gemm1..attn
  //   tab   f32  [2048,32,2] @ 25165824      524,288   rope_tab..attn
  //   kb    bf16             @ 25690112    4,194,304   ropek..attn
  //   vtb   bf16             @ 29884416    5,242,880   vt..attn
  //   xb    bf16 [4096,2048] @ 35127296   16,777,216   cvt..gemm1 (dead after)
  //   wqkvb bf16 [3072,2048] @ 51904512   12,582,912   cvt..gemm1 (dead after)
  //   aob = xb region (written by attn, xb dead)
  //   wob = wqkvb region (written after attn, wqkvb dead)
  unsigned short* qkvb = (unsigned short*)ws;
  float2* tab = (float2*)(ws + 25165824);
  unsigned short* kbuf = (unsigned short*)(ws + 25690112);
  unsigned short* vtb = (unsigned short*)(ws + 29884416);
  unsigned short* xb = (unsigned short*)(ws + 35127296);
  unsigned short* wqkvb = (unsigned short*)(ws + 51904512);
  unsigned short* aob = xb;
  unsigned short* wob = wqkvb;

  const int M = NB * LSEQ;  // 4096
  dim3 blk(256);

  rope_tab<<<(LSEQ * 32) / 256, blk, 0, stream>>>(tab);
  cvt_bf16<<<(M * DMODEL / 4 + 255) / 256, blk, 0, stream>>>(x, xb, M * DMODEL / 4);
  cvt_w3<<<(QKV_N * DMODEL / 4) / 256, blk, 0, stream>>>(Wq, Wk, Wv, wqkvb);

  // QKV projection -> bf16 qkvb
  gemm2<true><<<dim3(QKV_N / 128, M / 128), blk, 0, stream>>>(xb, wqkvb, qkvb, DMODEL, QKV_N);

  ropek_cvt2<<<(NB * LSEQ * 8 * 32) / 256, blk, 0, stream>>>(qkvb, tab, kbuf);
  vt_cvt2<<<dim3(LSEQ / 64, NHK, NB), blk, 0, stream>>>(qkvb, vtb);

  attn7<<<dim3(NHK, 64, NB), blk, 0, stream>>>(qkvb, tab, kbuf, vtb, aob);

  cvt_bf16<<<(DMODEL * DMODEL / 4 + 255) / 256, blk, 0, stream>>>(Wo, wob, DMODEL * DMODEL / 4);

  // output projection -> fp32 out
  gemm2<false><<<dim3(DMODEL / 128, M / 128), blk, 0, stream>>>(aob, wob, out, DMODEL, DMODEL);
}

// Round 9
// 314.329 us; speedup vs baseline: 1.1431x; 1.1431x over previous
//
#include <hip/hip_runtime.h>
#include <math.h>

#define NH 32
#define NHK 8
#define HD 64
#define DMODEL 2048
#define LSEQ 2048
#define NB 2
#define QKV_N 3072   // 2048 q + 512 k + 512 v

typedef __attribute__((ext_vector_type(8))) short short8;
typedef __attribute__((ext_vector_type(4))) float floatx4;

__device__ __forceinline__ unsigned short f2bf(float f) {
  unsigned u = __float_as_uint(f);
  return (unsigned short)((u + 0x7FFFu + ((u >> 16) & 1u)) >> 16);  // RNE
}
__device__ __forceinline__ float bf2f(unsigned short v) {
  return __uint_as_float((unsigned)v << 16);
}
__device__ __forceinline__ float fast_exp2(float x) {
#if __has_builtin(__builtin_amdgcn_exp2f)
  return __builtin_amdgcn_exp2f(x);
#else
  return __expf(x * 0.69314718f);
#endif
}
// pack bf16(hi),bf16(lo) from two fp32 by truncation: 1 v_perm_b32
__device__ __forceinline__ unsigned pack_bf_trunc(float hi, float lo) {
  return __builtin_amdgcn_perm(__float_as_uint(hi), __float_as_uint(lo), 0x07060302u);
}
// async 16B global->LDS; lds base must be wave-uniform, lanes land at base+lane*16
__device__ __forceinline__ void stage16(const unsigned short* g,
                                        unsigned short* lds_wave_base, int lane) {
#if __has_builtin(__builtin_amdgcn_global_load_lds)
  __builtin_amdgcn_global_load_lds(
      (const __attribute__((address_space(1))) void*)(g),
      (__attribute__((address_space(3))) void*)(lds_wave_base), 16, 0, 0);
#else
  *(uint4*)(lds_wave_base + lane * 8) = *(const uint4*)g;
#endif
}
// scatter variant: per-lane global address
__device__ __forceinline__ void stage16g(const char* g_lane,
                                         unsigned short* lds_wave_base, int lane) {
#if __has_builtin(__builtin_amdgcn_global_load_lds)
  __builtin_amdgcn_global_load_lds(
      (const __attribute__((address_space(1))) void*)(g_lane),
      (__attribute__((address_space(3))) void*)(lds_wave_base), 16, 0, 0);
#else
  *(uint4*)(lds_wave_base + lane * 8) = *(const uint4*)g_lane;
#endif
}

// ---------------------------------------------------------------------------
// RoPE cos/sin table: tab[l][d] = (cos, sin), l<2048, d<32
// ---------------------------------------------------------------------------
__global__ __launch_bounds__(256) void rope_tab(float2* __restrict__ tab) {
  int i = blockIdx.x * 256 + threadIdx.x;  // L*32
  int d = i & 31, l = i >> 5;
  float invf = (float)pow(10000.0, -(double)d / 32.0);
  float ang = (float)l * invf;
  double sd, cd;
  sincos((double)ang, &sd, &cd);
  tab[i] = make_float2((float)cd, (float)sd);
}

// ---------------------------------------------------------------------------
// fp32 -> bf16 elementwise convert
// ---------------------------------------------------------------------------
__global__ __launch_bounds__(256) void cvt_bf16(const float* __restrict__ src,
                                                unsigned short* __restrict__ dst,
                                                int n4) {
  int i = blockIdx.x * 256 + threadIdx.x;
  if (i >= n4) return;
  float4 v = ((const float4*)src)[i];
  ushort4 o;
  o.x = f2bf(v.x); o.y = f2bf(v.y); o.z = f2bf(v.z); o.w = f2bf(v.w);
  ((ushort4*)dst)[i] = o;
}

// ---------------------------------------------------------------------------
// Wq|Wk|Wv -> one bf16 buffer, single launch
// ---------------------------------------------------------------------------
__global__ __launch_bounds__(256) void cvt_w3(const float* __restrict__ Wq,
                                              const float* __restrict__ Wk,
                                              const float* __restrict__ Wv,
                                              unsigned short* __restrict__ dst) {
  const int NQ = DMODEL * DMODEL / 4, NK = 512 * DMODEL / 4;
  int i = blockIdx.x * 256 + threadIdx.x;  // 0..NQ+2*NK-1
  const float* src;
  int off;
  if (i < NQ) { src = Wq; off = i; }
  else if (i < NQ + NK) { src = Wk; off = i - NQ; }
  else { src = Wv; off = i - NQ - NK; }
  float4 v = ((const float4*)src)[off];
  ushort4 o;
  o.x = f2bf(v.x); o.y = f2bf(v.y); o.z = f2bf(v.z); o.w = f2bf(v.w);
  ((ushort4*)dst)[i] = o;
}

// ---------------------------------------------------------------------------
// bf16 NT GEMM, m97 structure: 128x128 tile, BK=32, global_load_lds width=16,
// unpadded LDS with XOR-swizzled 16B chunks.  BF16C: C written bf16.
// ---------------------------------------------------------------------------
template <bool BF16C>
__global__ __launch_bounds__(256) void gemm2(const unsigned short* __restrict__ A,
                                             const unsigned short* __restrict__ B,
                                             void* __restrict__ Cv, int K, int ldc) {
  __shared__ unsigned short As[128 * 32];
  __shared__ unsigned short Bs[128 * 32];
  const int tid = threadIdx.x;
  const int wave = tid >> 6, lane = tid & 63;
  const int quad = lane >> 4, l16 = lane & 15;
  const int m0 = blockIdx.y * 128, n0 = blockIdx.x * 128;
  const int wm = (wave & 1) * 64, wn = (wave >> 1) * 64;

  const int srow = wave * 16 + (lane >> 2);
  const int schunk = (lane & 3) ^ ((lane >> 2) & 3);
  const unsigned short* Asrc = A + (size_t)(m0 + srow) * K + schunk * 8;
  const unsigned short* Bsrc = B + (size_t)(n0 + srow) * K + schunk * 8;
  unsigned short* AdstL = &As[wave * 512];
  unsigned short* AdstH = &As[2048 + wave * 512];
  unsigned short* BdstL = &Bs[wave * 512];
  unsigned short* BdstH = &Bs[2048 + wave * 512];
  const size_t rstep = (size_t)64 * K;

  const int sw = (quad ^ (l16 & 3)) * 8;
  floatx4 acc[4][4] = {};

  for (int k0 = 0; k0 < K; k0 += 32) {
    __syncthreads();
    stage16(Asrc + k0, AdstL, lane);
    stage16(Asrc + rstep + k0, AdstH, lane);
    stage16(Bsrc + k0, BdstL, lane);
    stage16(Bsrc + rstep + k0, BdstH, lane);
    __syncthreads();
    short8 af[4], bfr[4];
#pragma unroll
    for (int i = 0; i < 4; ++i)
      af[i] = *(const short8*)&As[(wm + i * 16 + l16) * 32 + sw];
#pragma unroll
    for (int j = 0; j < 4; ++j)
      bfr[j] = *(const short8*)&Bs[(wn + j * 16 + l16) * 32 + sw];
#pragma unroll
    for (int i = 0; i < 4; ++i)
#pragma unroll
      for (int j = 0; j < 4; ++j)
        acc[i][j] = __builtin_amdgcn_mfma_f32_16x16x32_bf16(af[i], bfr[j], acc[i][j], 0, 0, 0);
  }

#pragma unroll
  for (int i = 0; i < 4; ++i)
#pragma unroll
    for (int j = 0; j < 4; ++j)
#pragma unroll
      for (int r = 0; r < 4; ++r) {
        size_t idx = (size_t)(m0 + wm + i * 16 + quad * 4 + r) * ldc + n0 + wn + j * 16 + l16;
        if (BF16C)
          ((unsigned short*)Cv)[idx] = f2bf(acc[i][j][r]);
        else
          ((float*)Cv)[idx] = acc[i][j][r];
      }
}

// ---------------------------------------------------------------------------
// RoPE k (bf16 in) -> kb [B, HK, L, 64] bf16
// ---------------------------------------------------------------------------
__global__ __launch_bounds__(256) void ropek_cvt2(const unsigned short* __restrict__ qkvb,
                                                  const float2* __restrict__ tab,
                                                  unsigned short* __restrict__ kb) {
  int t = blockIdx.x * 256 + threadIdx.x;  // B*L*8*32 threads
  int d = t & 31;
  int rest = t >> 5;
  int khead = rest & 7;
  int bl = rest >> 3;
  int l = bl & (LSEQ - 1);
  int b = bl >> 11;
  const unsigned short* src = qkvb + (size_t)bl * QKV_N + DMODEL + khead * HD;
  float2 cs = tab[(size_t)l * 32 + d];
  float x1 = bf2f(src[d]), x2 = bf2f(src[d + 32]);
  unsigned short* dst = kb + ((size_t)((b * NHK + khead) * LSEQ + l)) * HD;
  dst[d] = f2bf(x1 * cs.x - x2 * cs.y);
  dst[d + 32] = f2bf(x2 * cs.x + x1 * cs.y);
}

// ---------------------------------------------------------------------------
// V transpose (bf16 in): vtb [B, HK, 80, L] (rows 0..63 = V^T, row 64 = ones,
// rows 65..79 poison but harmless: bf16(0xAAAA) ~ -3e-13)
// ---------------------------------------------------------------------------
__global__ __launch_bounds__(256) void vt_cvt2(const unsigned short* __restrict__ qkvb,
                                               unsigned short* __restrict__ vtb) {
  __shared__ unsigned short Lt[64][72];
  const int tt = blockIdx.x, kh = blockIdx.y, b = blockIdx.z;
  const int tid = threadIdx.x;
  const unsigned short* src =
      qkvb + ((size_t)(b * LSEQ + tt * 64)) * QKV_N + DMODEL + 512 + kh * HD;
  {
    int row = tid >> 2, c0 = (tid & 3) * 16;
    *(uint4*)&Lt[row][c0] = *(const uint4*)(src + (size_t)row * QKV_N + c0);
    *(uint4*)&Lt[row][c0 + 8] = *(const uint4*)(src + (size_t)row * QKV_N + c0 + 8);
  }
  __syncthreads();
  {
    int d = tid >> 2, seg = tid & 3;
    unsigned short o[16];
#pragma unroll
    for (int k = 0; k < 16; ++k) o[k] = Lt[seg * 16 + k][d];
    unsigned short* dst =
        vtb + ((size_t)((b * NHK + kh) * 80 + d)) * LSEQ + tt * 64 + seg * 16;
    *(uint4*)dst = *(uint4*)o;
    *(uint4*)(dst + 8) = *(uint4*)(o + 8);
  }
  if (tid < 64)
    vtb[((size_t)((b * NHK + kh) * 80 + 64)) * LSEQ + tt * 64 + tid] = 0x3F80;  // 1.0
}

// ---------------------------------------------------------------------------
// attn8: flash MFMA causal GQA attention with SINGLE-BARRIER PING-PONG
// staging.  Grid (8=kh -> XCD pin, 32=pair, 2=b) = 512 UNIFORM blocks
// (subtile pair p & 63-p flattened into one 33-iteration pipeline; every
// block identical length -> perfect balance, the r8 lesson).  Per iter m:
// barrier (drains DMA for tile m, issued a full compute-phase earlier) ->
// issue async DMA for tile m+1 into the other K/V buffer -> compute tile m.
// Block = 4 waves = 4 q-heads of one kv group sharing the staged tiles.
// S^T orientation; RoPE fused into Q load; P round-trips wave-private LDS;
// row-sums via ones-row of V^T.
// ---------------------------------------------------------------------------
__global__ __launch_bounds__(256, 2) void attn8(const unsigned short* __restrict__ qkvb,
                                                const float2* __restrict__ tab,
                                                const unsigned short* __restrict__ kb,
                                                const unsigned short* __restrict__ vtb,
                                                unsigned short* __restrict__ out) {
  const int kh = blockIdx.x;  // 0..7 fastest -> XCD pin
  const int p = blockIdx.y;   // 0..31 pair index
  const int b = blockIdx.z;
  const int wave = threadIdx.x >> 6, lane = threadIdx.x & 63;
  const int quad = lane >> 4, l16 = lane & 15;
  const int h = kh * 4 + wave;

  __shared__ unsigned short Kbuf[2][64 * 64];   // 16 KB ping-pong [key][d]
  __shared__ unsigned short Vbuf[2][80 * 64];   // 20 KB ping-pong [d][key]
  __shared__ unsigned short Ps_all[4][32][72];  // 18 KB wave-private P tiles
  unsigned short(*Ps)[72] = Ps_all[wave];

  const char* kbaseB = (const char*)(kb + ((size_t)(b * NHK + kh) * LSEQ) * HD);
  const char* vbaseB = (const char*)(vtb + ((size_t)(b * NHK + kh) * 80) * LSEQ);
  const float QSCALE = 0.125f * 1.44269504f;  // 1/sqrt(64) * log2(e)

  short8 qf[2][2];
  floatx4 O[2][5];

  auto loadQ = [&](int qb) {
#pragma unroll
    for (int i = 0; i < 2; ++i) {
      const int tok = qb + i * 16 + l16;
      const unsigned short* qr =
          qkvb + ((size_t)(b * LSEQ + tok)) * QKV_N + h * HD + quad * 8;
      uint4 lo = *(const uint4*)qr;         // d = quad*8 .. +7
      uint4 hi = *(const uint4*)(qr + 32);  // d+32
      const float2* tr = tab + (size_t)tok * 32 + quad * 8;
      float4 cs01 = ((const float4*)tr)[0];
      float4 cs23 = ((const float4*)tr)[1];
      float4 cs45 = ((const float4*)tr)[2];
      float4 cs67 = ((const float4*)tr)[3];
      float cosv[8] = {cs01.x, cs01.z, cs23.x, cs23.z, cs45.x, cs45.z, cs67.x, cs67.z};
      float sinv[8] = {cs01.y, cs01.w, cs23.y, cs23.w, cs45.y, cs45.w, cs67.y, cs67.w};
      const unsigned short* plo = (const unsigned short*)&lo;
      const unsigned short* phi = (const unsigned short*)&hi;
      unsigned short olo[8], ohi[8];
#pragma unroll
      for (int j = 0; j < 8; ++j) {
        float x1 = bf2f(plo[j]), x2 = bf2f(phi[j]);
        olo[j] = f2bf((x1 * cosv[j] - x2 * sinv[j]) * QSCALE);
        ohi[j] = f2bf((x2 * cosv[j] + x1 * sinv[j]) * QSCALE);
      }
      qf[i][0] = *(const short8*)olo;
      qf[i][1] = *(const short8*)ohi;
    }
  };
  auto zeroO = [&]() {
#pragma unroll
    for (int i = 0; i < 2; ++i)
#pragma unroll
      for (int j = 0; j < 5; ++j) O[i][j] = (floatx4){0.f, 0.f, 0.f, 0.f};
  };
  auto epilogue = [&](int qb) {
#pragma unroll
    for (int i = 0; i < 2; ++i) {
      float lv = __shfl(O[i][4][0], l16);  // lanes 0..15 hold l for q=16i+l16
      float inv = 1.0f / lv;
      const size_t obase =
          ((size_t)(b * LSEQ + qb + i * 16 + l16)) * DMODEL + h * HD;
#pragma unroll
      for (int j = 0; j < 4; ++j) {
        uint2 w;
        w.x = (unsigned)f2bf(O[i][j][0] * inv) | ((unsigned)f2bf(O[i][j][1] * inv) << 16);
        w.y = (unsigned)f2bf(O[i][j][2] * inv) | ((unsigned)f2bf(O[i][j][3] * inv) << 16);
        *(uint2*)&out[obase + j * 16 + quad * 4] = w;
      }
    }
  };
  auto stageKV = [&](int bi, int kt) {
    unsigned short* Kd = Kbuf[bi];
    unsigned short* Vd = Vbuf[bi];
#pragma unroll
    for (int c = wave; c < 18; c += 4) {
      if (c < 8) {
        int o = c * 1024 + lane * 16;
        int row = o >> 7;                    // key 0..63
        int lgc = ((o >> 4) & 7) ^ (row & 7);
        stage16g(kbaseB + (size_t)(kt * 64 + row) * 128 + lgc * 16,
                 Kd + c * 512, lane);
      } else {
        int o = (c - 8) * 1024 + lane * 16;
        int row = o >> 7;                    // d-row 0..79
        int lgc = ((o >> 4) & 7) ^ (row & 7);
        stage16g(vbaseB + (size_t)row * (LSEQ * 2) + (size_t)kt * 128 + lgc * 16,
                 Vd + (c - 8) * 512, lane);
      }
    }
  };

  const int last0 = p >> 1;          // subtile a0 = p
  const int last1 = (63 - p) >> 1;   // subtile a1 = 63-p
  const int qb0 = p * 32, qb1 = (63 - p) * 32;
  const int N = last0 + last1 + 2;   // == 33 for all p

  loadQ(qb0);
  zeroO();
  stageKV(0, 0);
  int qb = qb0, lastk = last0;

#pragma unroll 1
  for (int m = 0; m < N; ++m) {
    __syncthreads();  // drains tile m's DMA (issued one compute-phase ago)

    // issue next tile's async DMA into the other buffer
    if (m + 1 < N) {
      int kt2 = (m + 1 > last0) ? (m - last0) : (m + 1);
      stageKV((m + 1) & 1, kt2);
    }
    // subtile transition: finish a0, switch to a1
    if (m == last0 + 1) {
      epilogue(qb0);
      zeroO();
      loadQ(qb1);
      qb = qb1;
      lastk = last1;
    }

    const int kt = (m > last0) ? (m - last0 - 1) : m;
    const unsigned short* Ks = Kbuf[m & 1];
    const unsigned short* Vs = Vbuf[m & 1];

    // ---- K frags from LDS (A-operand: m=key=16t+l16, k=d=32hf+quad*8+j) ----
    short8 kf[4][2];
#pragma unroll
    for (int t = 0; t < 4; ++t)
#pragma unroll
      for (int hf = 0; hf < 2; ++hf) {
        int row = t * 16 + l16;
        int phys = (4 * hf + quad) ^ (row & 7);
        kf[t][hf] = *(const short8*)&Ks[row * 64 + phys * 8];
      }

    // ---- S^T = K Q^T ----
    floatx4 st[4][2];
#pragma unroll
    for (int t = 0; t < 4; ++t)
#pragma unroll
      for (int i = 0; i < 2; ++i) {
        floatx4 z = {0.f, 0.f, 0.f, 0.f};
        z = __builtin_amdgcn_mfma_f32_16x16x32_bf16(kf[t][0], qf[i][0], z, 0, 0, 0);
        st[t][i] = __builtin_amdgcn_mfma_f32_16x16x32_bf16(kf[t][1], qf[i][1], z, 0, 0, 0);
      }

    // ---- P = exp2(S^T), causal mask only on the final kt (uniform branch) ----
    if (kt == lastk) {
      const int kofs = kt * 64 - qb;
#pragma unroll
      for (int t = 0; t < 4; ++t) {
        const int krow = kofs + 16 * t + quad * 4;
#pragma unroll
        for (int i = 0; i < 2; ++i) {
          const int qcol = 16 * i + l16;
          float sv[4];
#pragma unroll
          for (int r = 0; r < 4; ++r) {
            float v = st[t][i][r];
            if (krow + r > qcol) v = -1e30f;
            sv[r] = fast_exp2(v);
          }
          uint2 w;
          w.x = pack_bf_trunc(sv[1], sv[0]);
          w.y = pack_bf_trunc(sv[3], sv[2]);
          *(uint2*)&Ps[16 * i + l16][16 * t + quad * 4] = w;
        }
      }
    } else {
#pragma unroll
      for (int t = 0; t < 4; ++t)
#pragma unroll
        for (int i = 0; i < 2; ++i) {
          float sv[4];
#pragma unroll
          for (int r = 0; r < 4; ++r) sv[r] = fast_exp2(st[t][i][r]);
          uint2 w;
          w.x = pack_bf_trunc(sv[1], sv[0]);
          w.y = pack_bf_trunc(sv[3], sv[2]);
          *(uint2*)&Ps[16 * i + l16][16 * t + quad * 4] = w;
        }
    }

    // ---- O^T += V^T P^T ----
    short8 pf[2][2];
#pragma unroll
    for (int i = 0; i < 2; ++i)
#pragma unroll
      for (int hh = 0; hh < 2; ++hh)
        pf[i][hh] = *(const short8*)&Ps[16 * i + l16][32 * hh + quad * 8];
#pragma unroll
    for (int j = 0; j < 5; ++j) {
      int row = j * 16 + l16;
      short8 vf0 = *(const short8*)&Vs[row * 64 + ((quad ^ (row & 7)) * 8)];
      short8 vf1 = *(const short8*)&Vs[row * 64 + (((4 + quad) ^ (row & 7)) * 8)];
#pragma unroll
      for (int i = 0; i < 2; ++i) {
        O[i][j] = __builtin_amdgcn_mfma_f32_16x16x32_bf16(vf0, pf[i][0], O[i][j], 0, 0, 0);
        O[i][j] = __builtin_amdgcn_mfma_f32_16x16x32_bf16(vf1, pf[i][1], O[i][j], 0, 0, 0);
      }
    }
  }

  epilogue(qb1);
}

extern "C" void kernel_launch(void* const* d_in, const int* in_sizes, int n_in,
                              void* d_out, int out_size, void* d_ws,
                              size_t ws_size, hipStream_t stream) {
  const float* x = (const float*)d_in[0];
  const float* Wq = (const float*)d_in[1];
  const float* Wk = (const float*)d_in[2];
  const float* Wv = (const float*)d_in[3];
  const float* Wo = (const float*)d_in[4];
  float* out = (float*)d_out;

  char* ws = (char*)d_ws;
  // layout (peak 64.5 MB):
  //   qkvb  bf16 [4096,3072] @ 0          25,165,824   gemm1..attn
  //   tab   f32  [2048,32,2] @ 25165824      524,288   rope_tab..attn
  //   kb    bf16             @ 25690112    4,194,304   ropek..attn
  //   vtb   bf16             @ 29884416    5,242,880   vt..attn
  //   xb    bf16 [4096,2048] @ 35127296   16,777,216   cvt..gemm1 (dead after)
  //   wqkvb bf16 [3072,2048] @ 51904512   12,582,912   cvt..gemm1 (dead after)
  //   aob = xb region (written by attn, xb dead)
  //   wob = wqkvb region (written after attn, wqkvb dead)
  unsigned short* qkvb = (unsigned short*)ws;
  float2* tab = (float2*)(ws + 25165824);
  unsigned short* kbuf = (unsigned short*)(ws + 25690112);
  unsigned short* vtb = (unsigned short*)(ws + 29884416);
  unsigned short* xb = (unsigned short*)(ws + 35127296);
  unsigned short* wqkvb = (unsigned short*)(ws + 51904512);
  unsigned short* aob = xb;
  unsigned short* wob = wqkvb;

  const int M = NB * LSEQ;  // 4096
  dim3 blk(256);

  rope_tab<<<(LSEQ * 32) / 256, blk, 0, stream>>>(tab);
  cvt_bf16<<<(M * DMODEL / 4 + 255) / 256, blk, 0, stream>>>(x, xb, M * DMODEL / 4);
  cvt_w3<<<(QKV_N * DMODEL / 4) / 256, blk, 0, stream>>>(Wq, Wk, Wv, wqkvb);

  // QKV projection -> bf16 qkvb
  gemm2<true><<<dim3(QKV_N / 128, M / 128), blk, 0, stream>>>(xb, wqkvb, qkvb, DMODEL, QKV_N);

  ropek_cvt2<<<(NB * LSEQ * 8 * 32) / 256, blk, 0, stream>>>(qkvb, tab, kbuf);
  vt_cvt2<<<dim3(LSEQ / 64, NHK, NB), blk, 0, stream>>>(qkvb, vtb);

  attn8<<<dim3(NHK, 32, NB), blk, 0, stream>>>(qkvb, tab, kbuf, vtb, aob);

  cvt_bf16<<<(DMODEL * DMODEL / 4 + 255) / 256, blk, 0, stream>>>(Wo, wob, DMODEL * DMODEL / 4);

  // output projection -> fp32 out
  gemm2<false><<<dim3(DMODEL / 128, M / 128), blk, 0, stream>>>(aob, wob, out, DMODEL, DMODEL);
}